// Round 1
// baseline (981.325 us; speedup 1.0000x reference)
//
#include <hip/hip_runtime.h>
#include <math.h>

#define NMESH 128
#define NTOT (128*128*128)

// ---------- helpers ----------

__device__ inline void inv3x3(const float* __restrict__ c, float* inv, float* detOut) {
    float a = c[0], b = c[1], cc = c[2];
    float d = c[3], e = c[4], f  = c[5];
    float g = c[6], h = c[7], i  = c[8];
    float A = e * i - f * h;
    float B = f * g - d * i;
    float C = d * h - e * g;
    float det = a * A + b * B + cc * C;
    float r = 1.0f / det;
    inv[0] = A * r;              inv[1] = (cc * h - b * i) * r;  inv[2] = (b * f - cc * e) * r;
    inv[3] = B * r;              inv[4] = (a * i - cc * g) * r;  inv[5] = (cc * d - a * f) * r;
    inv[6] = C * r;              inv[7] = (b * g - a * h) * r;   inv[8] = (a * e - b * d) * r;
    *detOut = det;
}

// P3M order-4 assignment: weights + wrapped indices along one axis
__device__ inline void stencil1d(float rel, float* w, int* idx) {
    float fl = floorf(rel);
    int i0 = (int)fl;
    float x  = rel - (fl + 0.5f);
    float x2 = x * x, x3 = x2 * x;
    w[0] = (1.0f  - 6.0f  * x + 12.0f * x2 - 8.0f  * x3) * (1.0f / 48.0f);
    w[1] = (23.0f - 30.0f * x - 12.0f * x2 + 24.0f * x3) * (1.0f / 48.0f);
    w[2] = (23.0f + 30.0f * x - 12.0f * x2 - 24.0f * x3) * (1.0f / 48.0f);
    w[3] = (1.0f  + 6.0f  * x + 12.0f * x2 + 8.0f  * x3) * (1.0f / 48.0f);
    idx[0] = (i0 - 1) & 127;
    idx[1] = (i0    ) & 127;
    idx[2] = (i0 + 1) & 127;
    idx[3] = (i0 + 2) & 127;
}

__device__ inline void atom_stencil(const float* __restrict__ cell,
                                    const float* __restrict__ pos, int t,
                                    float* wx, float* wy, float* wz,
                                    int* ix, int* iy, int* iz) {
    float inv[9]; float det;
    inv3x3(cell, inv, &det);
    float px = pos[3 * t], py = pos[3 * t + 1], pz = pos[3 * t + 2];
    // rel[d] = sum_c pos[c] * inv(cell)[c][d]  * 128
    float relx = (px * inv[0] + py * inv[3] + pz * inv[6]) * 128.0f;
    float rely = (px * inv[1] + py * inv[4] + pz * inv[7]) * 128.0f;
    float relz = (px * inv[2] + py * inv[5] + pz * inv[8]) * 128.0f;
    stencil1d(relx, wx, ix);
    stencil1d(rely, wy, iy);
    stencil1d(relz, wz, iz);
}

// ---------- kernels ----------

__global__ void zero_kernel(float2* __restrict__ p) {
    int i = blockIdx.x * blockDim.x + threadIdx.x;
    if (i < NTOT) p[i] = make_float2(0.0f, 0.0f);
}

__global__ void scatter_kernel(const float* __restrict__ cell,
                               const float* __restrict__ pos,
                               const float* __restrict__ q,
                               float2* __restrict__ mesh, int n) {
    int t = blockIdx.x * blockDim.x + threadIdx.x;
    if (t >= n) return;
    float wx[4], wy[4], wz[4]; int ix[4], iy[4], iz[4];
    atom_stencil(cell, pos, t, wx, wy, wz, ix, iy, iz);
    float qc = q[t];
    #pragma unroll
    for (int i = 0; i < 4; ++i) {
        float qwx = qc * wx[i];
        int bx = ix[i] << 14;
        #pragma unroll
        for (int j = 0; j < 4; ++j) {
            float qwxy = qwx * wy[j];
            int bxy = bx | (iy[j] << 7);
            #pragma unroll
            for (int k = 0; k < 4; ++k) {
                atomicAdd(&mesh[bxy | iz[k]].x, qwxy * wz[k]);
            }
        }
    }
}

// 128-point radix-2 DIT FFT per line; SIGN=-1 forward, +1 inverse (unnormalized).
// stride = 1<<LOG2S; line b: base = (b>>LOG2S)*(stride*128) + (b & (stride-1))
template<int SIGN, int LOG2S>
__global__ __launch_bounds__(64) void fft128_pass(float2* __restrict__ d) {
    const int b = blockIdx.x;
    const int stride = 1 << LOG2S;
    const size_t base = ((size_t)(b >> LOG2S) << (LOG2S + 7)) + (size_t)(b & (stride - 1));
    __shared__ float re[128], im[128];
    const int t = threadIdx.x;

    #pragma unroll
    for (int e = t; e < 128; e += 64) {
        int r = (int)(__brev((unsigned)e) >> 25);   // 7-bit bit reversal
        float2 v = d[base + (size_t)r * stride];
        re[e] = v.x; im[e] = v.y;
    }
    __syncthreads();

    #pragma unroll
    for (int s = 1; s <= 7; ++s) {
        int half = 1 << (s - 1);
        int pos = t & (half - 1);
        int i = ((t >> (s - 1)) << s) | pos;
        int j = i + half;
        float ang = (float)SIGN * 3.14159265358979323846f * (float)pos / (float)half;
        float sn, cs;
        __sincosf(ang, &sn, &cs);
        float ar = re[j], ai = im[j];
        float tr = cs * ar - sn * ai;
        float ti = cs * ai + sn * ar;
        float br = re[i], bi = im[i];
        re[j] = br - tr; im[j] = bi - ti;
        re[i] = br + tr; im[i] = bi + ti;
        __syncthreads();
    }

    #pragma unroll
    for (int e = t; e < 128; e += 64) {
        d[base + (size_t)e * stride] = make_float2(re[e], im[e]);
    }
}

__global__ void apply_G_kernel(float2* __restrict__ d, const float* __restrict__ cell) {
    int f = blockIdx.x * blockDim.x + threadIdx.x;
    if (f >= NTOT) return;
    float inv[9]; float det;
    inv3x3(cell, inv, &det);
    int mz = f & 127, my = (f >> 7) & 127, mx = f >> 14;
    float fx = (mx < 64) ? (float)mx : (float)(mx - 128);
    float fy = (my < 64) ? (float)my : (float)(my - 128);
    float fz = (mz < 64) ? (float)mz : (float)(mz - 128);
    const float TWO_PI = 6.28318530717958647692f;
    // kvec[c] = 2*pi * sum_r m_r * inv(cell)[c][r]
    float kx = TWO_PI * (fx * inv[0] + fy * inv[1] + fz * inv[2]);
    float ky = TWO_PI * (fx * inv[3] + fy * inv[4] + fz * inv[5]);
    float kz = TWO_PI * (fx * inv[6] + fy * inv[7] + fz * inv[8]);
    float ksq = kx * kx + ky * ky + kz * kz;
    float invVol = 1.0f / fabsf(det);
    float G;
    if (ksq == 0.0f) {
        G = 0.0f;
    } else {
        const float FOUR_PI = 12.5663706143591729539f;
        G = FOUR_PI / ksq * __expf(-0.5f * ksq) * invVol;
    }
    float2 v = d[f];
    d[f] = make_float2(v.x * G, v.y * G);
}

__global__ void gather_kernel(const float* __restrict__ cell,
                              const float* __restrict__ pos,
                              const float* __restrict__ q,
                              const float2* __restrict__ mesh,
                              float* __restrict__ out, int n) {
    int t = blockIdx.x * blockDim.x + threadIdx.x;
    if (t >= n) return;
    float wx[4], wy[4], wz[4]; int ix[4], iy[4], iz[4];
    atom_stencil(cell, pos, t, wx, wy, wz, ix, iy, iz);
    float sum = 0.0f;
    #pragma unroll
    for (int i = 0; i < 4; ++i) {
        int bx = ix[i] << 14;
        float acc_i = 0.0f;
        #pragma unroll
        for (int j = 0; j < 4; ++j) {
            int bxy = bx | (iy[j] << 7);
            float acc_j = 0.0f;
            #pragma unroll
            for (int k = 0; k < 4; ++k) {
                acc_j += wz[k] * mesh[bxy | iz[k]].x;
            }
            acc_i += wy[j] * acc_j;
        }
        sum += wx[i] * acc_i;
    }
    // self-term: sqrt(2/pi)/sigma, sigma = 1
    out[t] = sum - q[t] * 0.79788456080286535588f;
}

// ---------- launch ----------

extern "C" void kernel_launch(void* const* d_in, const int* in_sizes, int n_in,
                              void* d_out, int out_size, void* d_ws, size_t ws_size,
                              hipStream_t stream) {
    const float* cell = (const float*)d_in[0];
    const float* pos  = (const float*)d_in[1];
    const float* q    = (const float*)d_in[2];
    float* out = (float*)d_out;
    const int n = in_sizes[2];                 // charges count = atoms

    float2* mesh = (float2*)d_ws;              // 128^3 complex = 16 MiB

    zero_kernel<<<(NTOT + 255) / 256, 256, 0, stream>>>(mesh);
    scatter_kernel<<<(n + 255) / 256, 256, 0, stream>>>(cell, pos, q, mesh, n);

    // forward FFT (sign = -1): z (stride 1), y (stride 128), x (stride 16384)
    fft128_pass<-1, 0 ><<<128 * 128, 64, 0, stream>>>(mesh);
    fft128_pass<-1, 7 ><<<128 * 128, 64, 0, stream>>>(mesh);
    fft128_pass<-1, 14><<<128 * 128, 64, 0, stream>>>(mesh);

    apply_G_kernel<<<(NTOT + 255) / 256, 256, 0, stream>>>(mesh, cell);

    // inverse FFT (sign = +1), unnormalized (norm="forward" inverse)
    fft128_pass<1, 0 ><<<128 * 128, 64, 0, stream>>>(mesh);
    fft128_pass<1, 7 ><<<128 * 128, 64, 0, stream>>>(mesh);
    fft128_pass<1, 14><<<128 * 128, 64, 0, stream>>>(mesh);

    gather_kernel<<<(n + 255) / 256, 256, 0, stream>>>(cell, pos, q, mesh, out, n);
}

// Round 2
// 424.124 us; speedup vs baseline: 2.3138x; 2.3138x over previous
//
#include <hip/hip_runtime.h>
#include <math.h>

#define NMESH 128
#define NTOT (128*128*128)
#define NBIN 32                 // bins per axis (4 cells per bin)
#define BINS (NBIN*NBIN*NBIN)
#define TS 16                   // scatter tile edge (cells)
#define NTILES (8*8*8)

// ---------- helpers ----------

__device__ inline void inv3x3(const float* __restrict__ c, float* inv, float* detOut) {
    float a = c[0], b = c[1], cc = c[2];
    float d = c[3], e = c[4], f  = c[5];
    float g = c[6], h = c[7], i  = c[8];
    float A = e * i - f * h;
    float B = f * g - d * i;
    float C = d * h - e * g;
    float det = a * A + b * B + cc * C;
    float r = 1.0f / det;
    inv[0] = A * r;              inv[1] = (cc * h - b * i) * r;  inv[2] = (b * f - cc * e) * r;
    inv[3] = B * r;              inv[4] = (a * i - cc * g) * r;  inv[5] = (cc * d - a * f) * r;
    inv[6] = C * r;              inv[7] = (b * g - a * h) * r;   inv[8] = (a * e - b * d) * r;
    *detOut = det;
}

__device__ inline void w4(float x, float* w) {
    float x2 = x * x, x3 = x2 * x;
    w[0] = (1.0f  - 6.0f  * x + 12.0f * x2 - 8.0f  * x3) * (1.0f / 48.0f);
    w[1] = (23.0f - 30.0f * x - 12.0f * x2 + 24.0f * x3) * (1.0f / 48.0f);
    w[2] = (23.0f + 30.0f * x - 12.0f * x2 - 24.0f * x3) * (1.0f / 48.0f);
    w[3] = (1.0f  + 6.0f  * x + 12.0f * x2 + 8.0f  * x3) * (1.0f / 48.0f);
}

// rel coords (fractional * 128) for atom t
__device__ inline void atom_rel(const float* __restrict__ cell,
                                const float* __restrict__ pos, int t,
                                float* rx, float* ry, float* rz) {
    float inv[9]; float det;
    inv3x3(cell, inv, &det);
    float px = pos[3 * t], py = pos[3 * t + 1], pz = pos[3 * t + 2];
    *rx = (px * inv[0] + py * inv[3] + pz * inv[6]) * 128.0f;
    *ry = (px * inv[1] + py * inv[4] + pz * inv[7]) * 128.0f;
    *rz = (px * inv[2] + py * inv[5] + pz * inv[8]) * 128.0f;
}

__device__ inline int bin_of(float rx, float ry, float rz) {
    int ix = ((int)floorf(rx)) & 127;
    int iy = ((int)floorf(ry)) & 127;
    int iz = ((int)floorf(rz)) & 127;
    return ((ix >> 2) * NBIN + (iy >> 2)) * NBIN + (iz >> 2);
}

// ---------- binning kernels ----------

__global__ void zero_int_kernel(int* __restrict__ p, int n) {
    int i = blockIdx.x * blockDim.x + threadIdx.x;
    if (i < n) p[i] = 0;
}

__global__ void hist_kernel(const float* __restrict__ cell, const float* __restrict__ pos,
                            int* __restrict__ hist, int n) {
    int t = blockIdx.x * blockDim.x + threadIdx.x;
    if (t >= n) return;
    float rx, ry, rz;
    atom_rel(cell, pos, t, &rx, &ry, &rz);
    atomicAdd(&hist[bin_of(rx, ry, rz)], 1);
}

__global__ __launch_bounds__(256) void scan_kernel(const int* __restrict__ hist,
                                                   int* __restrict__ offsets,
                                                   int* __restrict__ cursor) {
    __shared__ int partial[256];
    int t = threadIdx.x;
    int s = 0;
    for (int i = 0; i < BINS / 256; ++i) s += hist[t * (BINS / 256) + i];
    partial[t] = s;
    __syncthreads();
    if (t == 0) {
        int a = 0;
        for (int i = 0; i < 256; ++i) { int v = partial[i]; partial[i] = a; a += v; }
        offsets[BINS] = a;
    }
    __syncthreads();
    int run = partial[t];
    for (int i = 0; i < BINS / 256; ++i) {
        int b = t * (BINS / 256) + i;
        offsets[b] = run; cursor[b] = run;
        run += hist[b];
    }
}

__global__ void reorder_kernel(const float* __restrict__ cell, const float* __restrict__ pos,
                               const float* __restrict__ q, int* __restrict__ cursor,
                               float4* __restrict__ sorted, int* __restrict__ sortedIdx, int n) {
    int t = blockIdx.x * blockDim.x + threadIdx.x;
    if (t >= n) return;
    float rx, ry, rz;
    atom_rel(cell, pos, t, &rx, &ry, &rz);
    int p = atomicAdd(&cursor[bin_of(rx, ry, rz)], 1);
    sorted[p] = make_float4(rx, ry, rz, q[t]);
    sortedIdx[p] = t;
}

// ---------- LDS-tiled scatter (no global atomics) ----------

__global__ __launch_bounds__(256) void tile_scatter_kernel(const float4* __restrict__ atoms,
                                                           const int* __restrict__ offsets,
                                                           float2* __restrict__ mesh) {
    const int tile = blockIdx.x;                 // 512 tiles of 16^3 cells
    const int tz = tile & 7, ty = (tile >> 3) & 7, tx = tile >> 6;
    const int ox = tx << 4, oy = ty << 4, oz = tz << 4;
    __shared__ float acc[TS * TS * TS];          // [lx<<8 | ly<<4 | lz]
    for (int c = threadIdx.x; c < TS * TS * TS; c += 256) acc[c] = 0.0f;
    __syncthreads();

    const int wave = threadIdx.x >> 6, lane = threadIdx.x & 63;

    for (int p = wave; p < 36; p += 4) {
        int bx = (4 * tx - 1 + p / 6) & (NBIN - 1);
        int by = (4 * ty - 1 + p % 6) & (NBIN - 1);
        int zb0 = (4 * tz - 1) & (NBIN - 1);
        int runlo[2], runlen[2];
        if (zb0 + 6 <= NBIN) { runlo[0] = zb0; runlen[0] = 6; runlen[1] = 0; runlo[1] = 0; }
        else { runlo[0] = zb0; runlen[0] = NBIN - zb0; runlo[1] = 0; runlen[1] = 6 - (NBIN - zb0); }
        for (int r = 0; r < 2; ++r) {
            if (runlen[r] == 0) continue;
            int binBase = (bx * NBIN + by) * NBIN + runlo[r];
            int s = offsets[binBase];
            int e = offsets[binBase + runlen[r]];
            for (int i = s + lane; i < e; i += 64) {
                float4 a = atoms[i];
                float w[4];
                float wxv[4], wyv[4], wzv[4];
                int lxv[4], lyv[4], lzv[4];
                int nx = 0, ny = 0, nz = 0;
                {
                    float fl = floorf(a.x); int i0 = (int)fl; float x = a.x - fl - 0.5f; w4(x, w);
                    #pragma unroll
                    for (int s2 = 0; s2 < 4; ++s2) {
                        int cc = (i0 + s2 - 1) & 127; int l = (cc - ox) & 127;
                        if (l < TS) { lxv[nx] = l << 8; wxv[nx++] = w[s2]; }
                    }
                }
                {
                    float fl = floorf(a.y); int i0 = (int)fl; float x = a.y - fl - 0.5f; w4(x, w);
                    #pragma unroll
                    for (int s2 = 0; s2 < 4; ++s2) {
                        int cc = (i0 + s2 - 1) & 127; int l = (cc - oy) & 127;
                        if (l < TS) { lyv[ny] = l << 4; wyv[ny++] = w[s2]; }
                    }
                }
                {
                    float fl = floorf(a.z); int i0 = (int)fl; float x = a.z - fl - 0.5f; w4(x, w);
                    #pragma unroll
                    for (int s2 = 0; s2 < 4; ++s2) {
                        int cc = (i0 + s2 - 1) & 127; int l = (cc - oz) & 127;
                        if (l < TS) { lzv[nz] = l; wzv[nz++] = w[s2]; }
                    }
                }
                float qc = a.w;
                for (int i2 = 0; i2 < nx; ++i2) {
                    float qx = qc * wxv[i2];
                    for (int j = 0; j < ny; ++j) {
                        float qxy = qx * wyv[j];
                        int b = lxv[i2] | lyv[j];
                        for (int k = 0; k < nz; ++k)
                            atomicAdd(&acc[b | lzv[k]], qxy * wzv[k]);
                    }
                }
            }
        }
    }
    __syncthreads();

    // non-atomic flush: each cell owned by exactly one tile
    for (int c = threadIdx.x; c < TS * TS * TS; c += 256) {
        int lx = c >> 8, ly = (c >> 4) & 15, lz = c & 15;
        int g = ((ox + lx) << 14) | ((oy + ly) << 7) | (oz + lz);
        mesh[g] = make_float2(acc[c], 0.0f);
    }
}

// ---------- FFT ----------

template<int SIGN, int LOG2S>
__global__ __launch_bounds__(64) void fft128_pass(float2* __restrict__ d) {
    const int b = blockIdx.x;
    const int stride = 1 << LOG2S;
    const size_t base = ((size_t)(b >> LOG2S) << (LOG2S + 7)) + (size_t)(b & (stride - 1));
    __shared__ float re[128], im[128];
    const int t = threadIdx.x;

    #pragma unroll
    for (int e = t; e < 128; e += 64) {
        int r = (int)(__brev((unsigned)e) >> 25);
        float2 v = d[base + (size_t)r * stride];
        re[e] = v.x; im[e] = v.y;
    }
    __syncthreads();

    #pragma unroll
    for (int s = 1; s <= 7; ++s) {
        int half = 1 << (s - 1);
        int pos = t & (half - 1);
        int i = ((t >> (s - 1)) << s) | pos;
        int j = i + half;
        float ang = (float)SIGN * 3.14159265358979323846f * (float)pos / (float)half;
        float sn, cs;
        __sincosf(ang, &sn, &cs);
        float ar = re[j], ai = im[j];
        float tr = cs * ar - sn * ai;
        float ti = cs * ai + sn * ar;
        float br = re[i], bi = im[i];
        re[j] = br - tr; im[j] = bi - ti;
        re[i] = br + tr; im[i] = bi + ti;
        __syncthreads();
    }

    #pragma unroll
    for (int e = t; e < 128; e += 64) {
        d[base + (size_t)e * stride] = make_float2(re[e], im[e]);
    }
}

__global__ void apply_G_kernel(float2* __restrict__ d, const float* __restrict__ cell) {
    int f = blockIdx.x * blockDim.x + threadIdx.x;
    if (f >= NTOT) return;
    float inv[9]; float det;
    inv3x3(cell, inv, &det);
    int mz = f & 127, my = (f >> 7) & 127, mx = f >> 14;
    float fx = (mx < 64) ? (float)mx : (float)(mx - 128);
    float fy = (my < 64) ? (float)my : (float)(my - 128);
    float fz = (mz < 64) ? (float)mz : (float)(mz - 128);
    const float TWO_PI = 6.28318530717958647692f;
    float kx = TWO_PI * (fx * inv[0] + fy * inv[1] + fz * inv[2]);
    float ky = TWO_PI * (fx * inv[3] + fy * inv[4] + fz * inv[5]);
    float kz = TWO_PI * (fx * inv[6] + fy * inv[7] + fz * inv[8]);
    float ksq = kx * kx + ky * ky + kz * kz;
    float invVol = 1.0f / fabsf(det);
    float G;
    if (ksq == 0.0f) {
        G = 0.0f;
    } else {
        const float FOUR_PI = 12.5663706143591729539f;
        G = FOUR_PI / ksq * __expf(-0.5f * ksq) * invVol;
    }
    float2 v = d[f];
    d[f] = make_float2(v.x * G, v.y * G);
}

// ---------- gather (sorted order for L2 locality) ----------

__global__ void gather_kernel(const float4* __restrict__ sorted, const int* __restrict__ sortedIdx,
                              const float2* __restrict__ mesh, float* __restrict__ out, int n) {
    int t = blockIdx.x * blockDim.x + threadIdx.x;
    if (t >= n) return;
    float4 a = sorted[t];
    float wx[4], wy[4], wz[4];
    int ix[4], iy[4], iz[4];
    {
        float fl = floorf(a.x); int i0 = (int)fl; float x = a.x - fl - 0.5f; w4(x, wx);
        #pragma unroll
        for (int s = 0; s < 4; ++s) ix[s] = (i0 + s - 1) & 127;
    }
    {
        float fl = floorf(a.y); int i0 = (int)fl; float x = a.y - fl - 0.5f; w4(x, wy);
        #pragma unroll
        for (int s = 0; s < 4; ++s) iy[s] = (i0 + s - 1) & 127;
    }
    {
        float fl = floorf(a.z); int i0 = (int)fl; float x = a.z - fl - 0.5f; w4(x, wz);
        #pragma unroll
        for (int s = 0; s < 4; ++s) iz[s] = (i0 + s - 1) & 127;
    }
    float sum = 0.0f;
    #pragma unroll
    for (int i = 0; i < 4; ++i) {
        int bx = ix[i] << 14;
        float acc_i = 0.0f;
        #pragma unroll
        for (int j = 0; j < 4; ++j) {
            int bxy = bx | (iy[j] << 7);
            float acc_j = 0.0f;
            #pragma unroll
            for (int k = 0; k < 4; ++k) {
                acc_j += wz[k] * mesh[bxy | iz[k]].x;
            }
            acc_i += wy[j] * acc_j;
        }
        sum += wx[i] * acc_i;
    }
    out[sortedIdx[t]] = sum - a.w * 0.79788456080286535588f;
}

// ---------- fallback (plain atomic scatter) in case ws is tight ----------

__global__ void zero_mesh_kernel(float2* __restrict__ p) {
    int i = blockIdx.x * blockDim.x + threadIdx.x;
    if (i < NTOT) p[i] = make_float2(0.0f, 0.0f);
}

__global__ void scatter_atomic_kernel(const float* __restrict__ cell, const float* __restrict__ pos,
                                      const float* __restrict__ q, float2* __restrict__ mesh, int n) {
    int t = blockIdx.x * blockDim.x + threadIdx.x;
    if (t >= n) return;
    float rx, ry, rz;
    atom_rel(cell, pos, t, &rx, &ry, &rz);
    float wx[4], wy[4], wz[4];
    int ix[4], iy[4], iz[4];
    { float fl = floorf(rx); int i0 = (int)fl; float x = rx - fl - 0.5f; w4(x, wx);
      for (int s = 0; s < 4; ++s) ix[s] = (i0 + s - 1) & 127; }
    { float fl = floorf(ry); int i0 = (int)fl; float x = ry - fl - 0.5f; w4(x, wy);
      for (int s = 0; s < 4; ++s) iy[s] = (i0 + s - 1) & 127; }
    { float fl = floorf(rz); int i0 = (int)fl; float x = rz - fl - 0.5f; w4(x, wz);
      for (int s = 0; s < 4; ++s) iz[s] = (i0 + s - 1) & 127; }
    float qc = q[t];
    for (int i = 0; i < 4; ++i) {
        float qx = qc * wx[i]; int bx = ix[i] << 14;
        for (int j = 0; j < 4; ++j) {
            float qxy = qx * wy[j]; int bxy = bx | (iy[j] << 7);
            for (int k = 0; k < 4; ++k) atomicAdd(&mesh[bxy | iz[k]].x, qxy * wz[k]);
        }
    }
}

__global__ void gather_plain_kernel(const float* __restrict__ cell, const float* __restrict__ pos,
                                    const float* __restrict__ q, const float2* __restrict__ mesh,
                                    float* __restrict__ out, int n) {
    int t = blockIdx.x * blockDim.x + threadIdx.x;
    if (t >= n) return;
    float rx, ry, rz;
    atom_rel(cell, pos, t, &rx, &ry, &rz);
    float wx[4], wy[4], wz[4];
    int ix[4], iy[4], iz[4];
    { float fl = floorf(rx); int i0 = (int)fl; float x = rx - fl - 0.5f; w4(x, wx);
      for (int s = 0; s < 4; ++s) ix[s] = (i0 + s - 1) & 127; }
    { float fl = floorf(ry); int i0 = (int)fl; float x = ry - fl - 0.5f; w4(x, wy);
      for (int s = 0; s < 4; ++s) iy[s] = (i0 + s - 1) & 127; }
    { float fl = floorf(rz); int i0 = (int)fl; float x = rz - fl - 0.5f; w4(x, wz);
      for (int s = 0; s < 4; ++s) iz[s] = (i0 + s - 1) & 127; }
    float sum = 0.0f;
    for (int i = 0; i < 4; ++i) {
        int bx = ix[i] << 14; float ai = 0.0f;
        for (int j = 0; j < 4; ++j) {
            int bxy = bx | (iy[j] << 7); float aj = 0.0f;
            for (int k = 0; k < 4; ++k) aj += wz[k] * mesh[bxy | iz[k]].x;
            ai += wy[j] * aj;
        }
        sum += wx[i] * ai;
    }
    out[t] = sum - q[t] * 0.79788456080286535588f;
}

// ---------- launch ----------

extern "C" void kernel_launch(void* const* d_in, const int* in_sizes, int n_in,
                              void* d_out, int out_size, void* d_ws, size_t ws_size,
                              hipStream_t stream) {
    const float* cell = (const float*)d_in[0];
    const float* pos  = (const float*)d_in[1];
    const float* q    = (const float*)d_in[2];
    float* out = (float*)d_out;
    const int n = in_sizes[2];

    char* ws = (char*)d_ws;
    size_t o = 0;
    float4* sorted   = (float4*)(ws + o); o += (size_t)n * 16;
    int* sortedIdx   = (int*)(ws + o);    o += (size_t)n * 4;  o = (o + 255) & ~(size_t)255;
    int* hist        = (int*)(ws + o);    o += (size_t)BINS * 4;
    int* offsets     = (int*)(ws + o);    o += (size_t)(BINS + 1) * 4; o = (o + 255) & ~(size_t)255;
    int* cursor      = (int*)(ws + o);    o += (size_t)BINS * 4; o = (o + 255) & ~(size_t)255;
    float2* mesh     = (float2*)(ws + o); o += (size_t)NTOT * 8;

    const bool sortedPath = (ws_size >= o);
    if (!sortedPath) {
        mesh = (float2*)d_ws;
        zero_mesh_kernel<<<(NTOT + 255) / 256, 256, 0, stream>>>(mesh);
        scatter_atomic_kernel<<<(n + 255) / 256, 256, 0, stream>>>(cell, pos, q, mesh, n);
    } else {
        zero_int_kernel<<<(BINS + 255) / 256, 256, 0, stream>>>(hist, BINS);
        hist_kernel<<<(n + 255) / 256, 256, 0, stream>>>(cell, pos, hist, n);
        scan_kernel<<<1, 256, 0, stream>>>(hist, offsets, cursor);
        reorder_kernel<<<(n + 255) / 256, 256, 0, stream>>>(cell, pos, q, cursor, sorted, sortedIdx, n);
        tile_scatter_kernel<<<NTILES, 256, 0, stream>>>(sorted, offsets, mesh);
    }

    fft128_pass<-1, 0 ><<<128 * 128, 64, 0, stream>>>(mesh);
    fft128_pass<-1, 7 ><<<128 * 128, 64, 0, stream>>>(mesh);
    fft128_pass<-1, 14><<<128 * 128, 64, 0, stream>>>(mesh);

    apply_G_kernel<<<(NTOT + 255) / 256, 256, 0, stream>>>(mesh, cell);

    fft128_pass<1, 0 ><<<128 * 128, 64, 0, stream>>>(mesh);
    fft128_pass<1, 7 ><<<128 * 128, 64, 0, stream>>>(mesh);
    fft128_pass<1, 14><<<128 * 128, 64, 0, stream>>>(mesh);

    if (sortedPath) {
        gather_kernel<<<(n + 255) / 256, 256, 0, stream>>>(sorted, sortedIdx, mesh, out, n);
    } else {
        gather_plain_kernel<<<(n + 255) / 256, 256, 0, stream>>>(cell, pos, q, mesh, out, n);
    }
}

// Round 3
// 228.887 us; speedup vs baseline: 4.2874x; 1.8530x over previous
//
#include <hip/hip_runtime.h>
#include <math.h>

#define NMESH 128
#define NTOT (128*128*128)
#define NBIN 32                 // bins per axis (4 cells per bin)
#define BINS (NBIN*NBIN*NBIN)
#define TS 16                   // scatter tile edge (cells)
#define NTILES (8*8*8)

#define PI_F      3.14159265358979323846f
#define TWO_PI_F  6.28318530717958647692f
#define FOUR_PI_F 12.5663706143591729539f

// skewed LDS index: breaks power-of-2 bank conflicts, injective for i<128
#define IDX(i) ((i) + ((i) >> 5))
#define LDSW 132

// ---------- helpers ----------

__device__ inline void inv3x3(const float* __restrict__ c, float* inv, float* detOut) {
    float a = c[0], b = c[1], cc = c[2];
    float d = c[3], e = c[4], f  = c[5];
    float g = c[6], h = c[7], i  = c[8];
    float A = e * i - f * h;
    float B = f * g - d * i;
    float C = d * h - e * g;
    float det = a * A + b * B + cc * C;
    float r = 1.0f / det;
    inv[0] = A * r;              inv[1] = (cc * h - b * i) * r;  inv[2] = (b * f - cc * e) * r;
    inv[3] = B * r;              inv[4] = (a * i - cc * g) * r;  inv[5] = (cc * d - a * f) * r;
    inv[6] = C * r;              inv[7] = (b * g - a * h) * r;   inv[8] = (a * e - b * d) * r;
    *detOut = det;
}

__device__ inline void w4(float x, float* w) {
    float x2 = x * x, x3 = x2 * x;
    w[0] = (1.0f  - 6.0f  * x + 12.0f * x2 - 8.0f  * x3) * (1.0f / 48.0f);
    w[1] = (23.0f - 30.0f * x - 12.0f * x2 + 24.0f * x3) * (1.0f / 48.0f);
    w[2] = (23.0f + 30.0f * x - 12.0f * x2 - 24.0f * x3) * (1.0f / 48.0f);
    w[3] = (1.0f  + 6.0f  * x + 12.0f * x2 + 8.0f  * x3) * (1.0f / 48.0f);
}

__device__ inline void atom_rel(const float* __restrict__ cell,
                                const float* __restrict__ pos, int t,
                                float* rx, float* ry, float* rz) {
    float inv[9]; float det;
    inv3x3(cell, inv, &det);
    float px = pos[3 * t], py = pos[3 * t + 1], pz = pos[3 * t + 2];
    *rx = (px * inv[0] + py * inv[3] + pz * inv[6]) * 128.0f;
    *ry = (px * inv[1] + py * inv[4] + pz * inv[7]) * 128.0f;
    *rz = (px * inv[2] + py * inv[5] + pz * inv[8]) * 128.0f;
}

__device__ inline int bin_of(float rx, float ry, float rz) {
    int ix = ((int)floorf(rx)) & 127;
    int iy = ((int)floorf(ry)) & 127;
    int iz = ((int)floorf(rz)) & 127;
    return ((ix >> 2) * NBIN + (iy >> 2)) * NBIN + (iz >> 2);
}

// ---------- binning ----------

__global__ void zero_int_kernel(int* __restrict__ p, int n) {
    int i = blockIdx.x * blockDim.x + threadIdx.x;
    if (i < n) p[i] = 0;
}

__global__ void hist_kernel(const float* __restrict__ cell, const float* __restrict__ pos,
                            int* __restrict__ hist, int n) {
    int t = blockIdx.x * blockDim.x + threadIdx.x;
    if (t >= n) return;
    float rx, ry, rz;
    atom_rel(cell, pos, t, &rx, &ry, &rz);
    atomicAdd(&hist[bin_of(rx, ry, rz)], 1);
}

__global__ __launch_bounds__(256) void scan_kernel(const int* __restrict__ hist,
                                                   int* __restrict__ offsets,
                                                   int* __restrict__ cursor) {
    const int PER = BINS / 256;          // 128 bins per thread
    int t = threadIdx.x;
    int base = t * PER;
    int s = 0;
    for (int i = 0; i < PER; ++i) s += hist[base + i];
    // inclusive shuffle-scan over 256 threads
    int lane = t & 63, wv = t >> 6;
    int v = s;
    #pragma unroll
    for (int d2 = 1; d2 < 64; d2 <<= 1) {
        int o = __shfl_up(v, d2, 64);
        if (lane >= d2) v += o;
    }
    __shared__ int wsum[4];
    if (lane == 63) wsum[wv] = v;
    __syncthreads();
    int add = 0;
    for (int k = 0; k < wv; ++k) add += wsum[k];
    int run = v - s + add;               // exclusive prefix of this thread's chunk
    for (int i = 0; i < PER; ++i) {
        int b = base + i;
        offsets[b] = run; cursor[b] = run;
        run += hist[b];
    }
    if (t == 255) offsets[BINS] = run;
}

__global__ void reorder_kernel(const float* __restrict__ cell, const float* __restrict__ pos,
                               const float* __restrict__ q, int* __restrict__ cursor,
                               float4* __restrict__ sorted, int* __restrict__ sortedIdx, int n) {
    int t = blockIdx.x * blockDim.x + threadIdx.x;
    if (t >= n) return;
    float rx, ry, rz;
    atom_rel(cell, pos, t, &rx, &ry, &rz);
    int p = atomicAdd(&cursor[bin_of(rx, ry, rz)], 1);
    sorted[p] = make_float4(rx, ry, rz, q[t]);
    sortedIdx[p] = t;
}

// ---------- LDS-tiled scatter (no global atomics), 512 threads ----------

__global__ __launch_bounds__(512) void tile_scatter_kernel(const float4* __restrict__ atoms,
                                                           const int* __restrict__ offsets,
                                                           float2* __restrict__ mesh) {
    const int tile = blockIdx.x;
    const int tz = tile & 7, ty = (tile >> 3) & 7, tx = tile >> 6;
    const int ox = tx << 4, oy = ty << 4, oz = tz << 4;
    __shared__ float acc[TS * TS * TS];
    for (int c = threadIdx.x; c < TS * TS * TS; c += 512) acc[c] = 0.0f;
    __syncthreads();

    const int wave = threadIdx.x >> 6, lane = threadIdx.x & 63;

    for (int p = wave; p < 36; p += 8) {
        int bx = (4 * tx - 1 + p / 6) & (NBIN - 1);
        int by = (4 * ty - 1 + p % 6) & (NBIN - 1);
        int zb0 = (4 * tz - 1) & (NBIN - 1);
        int runlo[2], runlen[2];
        if (zb0 + 6 <= NBIN) { runlo[0] = zb0; runlen[0] = 6; runlen[1] = 0; runlo[1] = 0; }
        else { runlo[0] = zb0; runlen[0] = NBIN - zb0; runlo[1] = 0; runlen[1] = 6 - (NBIN - zb0); }
        for (int r = 0; r < 2; ++r) {
            if (runlen[r] == 0) continue;
            int binBase = (bx * NBIN + by) * NBIN + runlo[r];
            int s = offsets[binBase];
            int e = offsets[binBase + runlen[r]];
            for (int i = s + lane; i < e; i += 64) {
                float4 a = atoms[i];
                float w[4];
                float wxv[4], wyv[4], wzv[4];
                int lxv[4], lyv[4], lzv[4];
                int nx = 0, ny = 0, nz = 0;
                {
                    float fl = floorf(a.x); int i0 = (int)fl; float x = a.x - fl - 0.5f; w4(x, w);
                    #pragma unroll
                    for (int s2 = 0; s2 < 4; ++s2) {
                        int cc = (i0 + s2 - 1) & 127; int l = (cc - ox) & 127;
                        if (l < TS) { lxv[nx] = l << 8; wxv[nx++] = w[s2]; }
                    }
                }
                {
                    float fl = floorf(a.y); int i0 = (int)fl; float x = a.y - fl - 0.5f; w4(x, w);
                    #pragma unroll
                    for (int s2 = 0; s2 < 4; ++s2) {
                        int cc = (i0 + s2 - 1) & 127; int l = (cc - oy) & 127;
                        if (l < TS) { lyv[ny] = l << 4; wyv[ny++] = w[s2]; }
                    }
                }
                {
                    float fl = floorf(a.z); int i0 = (int)fl; float x = a.z - fl - 0.5f; w4(x, w);
                    #pragma unroll
                    for (int s2 = 0; s2 < 4; ++s2) {
                        int cc = (i0 + s2 - 1) & 127; int l = (cc - oz) & 127;
                        if (l < TS) { lzv[nz] = l; wzv[nz++] = w[s2]; }
                    }
                }
                float qc = a.w;
                for (int i2 = 0; i2 < nx; ++i2) {
                    float qx = qc * wxv[i2];
                    for (int j = 0; j < ny; ++j) {
                        float qxy = qx * wyv[j];
                        int b = lxv[i2] | lyv[j];
                        for (int k = 0; k < nz; ++k)
                            atomicAdd(&acc[b | lzv[k]], qxy * wzv[k]);
                    }
                }
            }
        }
    }
    __syncthreads();

    for (int c = threadIdx.x; c < TS * TS * TS; c += 512) {
        int lx = c >> 8, ly = (c >> 4) & 15, lz = c & 15;
        int g = ((ox + lx) << 14) | ((oy + ly) << 7) | (oz + lz);
        mesh[g] = make_float2(acc[c], 0.0f);
    }
}

// ---------- batched FFT: 8 lines per 512-thread block ----------
// AXIS==2: z-lines (stride 1); AXIS==1: y-lines (stride 128); elements for
// 8 consecutive z per block (dz-fast loads = 64B coalesced chunks).

template<int AXIS>
__device__ inline size_t gaddr(int b, int l, int e) {
    if (AXIS == 2) return ((size_t)b << 10) + ((size_t)l << 7) + (size_t)e;
    if (AXIS == 1) return ((size_t)(b >> 4) << 14) + ((size_t)e << 7) + (size_t)((b & 15) << 3) + l;
    return ((size_t)e << 14) + ((size_t)(b >> 4) << 7) + (size_t)((b & 15) << 3) + l;
}

template<int AXIS>
__device__ inline void split_u(int u, int* l, int* e) {
    if (AXIS == 2) { *l = u >> 7; *e = u & 127; }
    else           { *l = u & 7;  *e = u >> 3;  }
}

// DIT pass: loads global natural -> LDS bit-reversed, 7 stages, stores natural.
template<int SIGN, int AXIS, bool REALOUT>
__global__ __launch_bounds__(512) void fft_dit(float2* __restrict__ d, float* __restrict__ rout) {
    __shared__ float re[8][LDSW], im[8][LDSW];
    const int t = threadIdx.x, b = blockIdx.x;

    for (int u = t; u < 1024; u += 512) {
        int l, e; split_u<AXIS>(u, &l, &e);
        float2 v = d[gaddr<AXIS>(b, l, e)];
        int r = (int)(__brev((unsigned)e) >> 25);
        re[l][IDX(r)] = v.x; im[l][IDX(r)] = v.y;
    }
    __syncthreads();

    const int w = t >> 6, lane = t & 63;
    #pragma unroll
    for (int s = 1; s <= 7; ++s) {
        int half = 1 << (s - 1);
        int pos = lane & (half - 1);
        int i = ((lane >> (s - 1)) << s) | pos;
        int j = i + half;
        float ang = (float)SIGN * PI_F * (float)pos / (float)half;
        float sn, cs; __sincosf(ang, &sn, &cs);
        int ii = IDX(i), jj = IDX(j);
        float ar = re[w][jj], ai = im[w][jj];
        float tr = cs * ar - sn * ai;
        float ti = cs * ai + sn * ar;
        float br = re[w][ii], bi = im[w][ii];
        re[w][jj] = br - tr; im[w][jj] = bi - ti;
        re[w][ii] = br + tr; im[w][ii] = bi + ti;
        __syncthreads();
    }

    for (int u = t; u < 1024; u += 512) {
        int l, e; split_u<AXIS>(u, &l, &e);
        if (REALOUT) rout[gaddr<AXIS>(b, l, e)] = re[l][IDX(e)];
        else         d[gaddr<AXIS>(b, l, e)] = make_float2(re[l][IDX(e)], im[l][IDX(e)]);
    }
}

// Fused x-axis: forward DIF -> G(k) multiply (bit-reversed order) -> inverse DIT.
__global__ __launch_bounds__(512) void fftX_G_kernel(float2* __restrict__ d,
                                                     const float* __restrict__ cell) {
    __shared__ float re[8][LDSW], im[8][LDSW];
    const int t = threadIdx.x, b = blockIdx.x;
    const int y = b >> 4, z0 = (b & 15) << 3;

    for (int u = t; u < 1024; u += 512) {
        int l = u & 7, e = u >> 3;
        float2 v = d[((size_t)e << 14) + (size_t)(y << 7) + (size_t)(z0 + l)];
        re[l][IDX(e)] = v.x; im[l][IDX(e)] = v.y;
    }
    __syncthreads();

    const int w = t >> 6, lane = t & 63;

    // forward DIF (natural in -> bit-reversed out), sign = -1
    #pragma unroll
    for (int s = 7; s >= 1; --s) {
        int half = 1 << (s - 1);
        int pos = lane & (half - 1);
        int i = ((lane >> (s - 1)) << s) | pos;
        int j = i + half;
        float ang = -PI_F * (float)pos / (float)half;
        float sn, cs; __sincosf(ang, &sn, &cs);
        int ii = IDX(i), jj = IDX(j);
        float ar = re[w][ii], ai = im[w][ii];
        float br = re[w][jj], bi = im[w][jj];
        re[w][ii] = ar + br;   im[w][ii] = ai + bi;
        float dr = ar - br, di = ai - bi;
        re[w][jj] = cs * dr - sn * di;
        im[w][jj] = cs * di + sn * dr;
        __syncthreads();
    }

    // G(k) multiply: LDS position p holds spectrum at kx-index rev7(p); line w: ky=y, kz=z0+w
    {
        float inv[9]; float det; inv3x3(cell, inv, &det);
        float invVol = 1.0f / fabsf(det);
        int my = y, mz = z0 + w;
        float fy = (my < 64) ? (float)my : (float)(my - 128);
        float fz = (mz < 64) ? (float)mz : (float)(mz - 128);
        for (int p = lane; p < 128; p += 64) {
            int mx = (int)(__brev((unsigned)p) >> 25);
            float fx = (mx < 64) ? (float)mx : (float)(mx - 128);
            float kx = TWO_PI_F * (fx * inv[0] + fy * inv[1] + fz * inv[2]);
            float ky = TWO_PI_F * (fx * inv[3] + fy * inv[4] + fz * inv[5]);
            float kz = TWO_PI_F * (fx * inv[6] + fy * inv[7] + fz * inv[8]);
            float ksq = kx * kx + ky * ky + kz * kz;
            float G = (ksq == 0.0f) ? 0.0f
                      : FOUR_PI_F / ksq * __expf(-0.5f * ksq) * invVol;
            re[w][IDX(p)] *= G; im[w][IDX(p)] *= G;
        }
    }
    __syncthreads();

    // inverse DIT (bit-reversed in -> natural out), sign = +1
    #pragma unroll
    for (int s = 1; s <= 7; ++s) {
        int half = 1 << (s - 1);
        int pos = lane & (half - 1);
        int i = ((lane >> (s - 1)) << s) | pos;
        int j = i + half;
        float ang = PI_F * (float)pos / (float)half;
        float sn, cs; __sincosf(ang, &sn, &cs);
        int ii = IDX(i), jj = IDX(j);
        float ar = re[w][jj], ai = im[w][jj];
        float tr = cs * ar - sn * ai;
        float ti = cs * ai + sn * ar;
        float br = re[w][ii], bi = im[w][ii];
        re[w][jj] = br - tr; im[w][jj] = bi - ti;
        re[w][ii] = br + tr; im[w][ii] = bi + ti;
        __syncthreads();
    }

    for (int u = t; u < 1024; u += 512) {
        int l = u & 7, e = u >> 3;
        d[((size_t)e << 14) + (size_t)(y << 7) + (size_t)(z0 + l)] =
            make_float2(re[l][IDX(e)], im[l][IDX(e)]);
    }
}

// ---------- gather ----------

template<bool REAL>
__global__ void gather_kernel(const float4* __restrict__ sorted, const int* __restrict__ sortedIdx,
                              const float2* __restrict__ mesh, const float* __restrict__ rmesh,
                              float* __restrict__ out, int n) {
    int t = blockIdx.x * blockDim.x + threadIdx.x;
    if (t >= n) return;
    float4 a = sorted[t];
    float wx[4], wy[4], wz[4];
    int ix[4], iy[4], iz[4];
    {
        float fl = floorf(a.x); int i0 = (int)fl; float x = a.x - fl - 0.5f; w4(x, wx);
        #pragma unroll
        for (int s = 0; s < 4; ++s) ix[s] = (i0 + s - 1) & 127;
    }
    {
        float fl = floorf(a.y); int i0 = (int)fl; float x = a.y - fl - 0.5f; w4(x, wy);
        #pragma unroll
        for (int s = 0; s < 4; ++s) iy[s] = (i0 + s - 1) & 127;
    }
    {
        float fl = floorf(a.z); int i0 = (int)fl; float x = a.z - fl - 0.5f; w4(x, wz);
        #pragma unroll
        for (int s = 0; s < 4; ++s) iz[s] = (i0 + s - 1) & 127;
    }
    float sum = 0.0f;
    #pragma unroll
    for (int i = 0; i < 4; ++i) {
        int bx = ix[i] << 14;
        float acc_i = 0.0f;
        #pragma unroll
        for (int j = 0; j < 4; ++j) {
            int bxy = bx | (iy[j] << 7);
            float acc_j = 0.0f;
            #pragma unroll
            for (int k = 0; k < 4; ++k) {
                acc_j += wz[k] * (REAL ? rmesh[bxy | iz[k]] : mesh[bxy | iz[k]].x);
            }
            acc_i += wy[j] * acc_j;
        }
        sum += wx[i] * acc_i;
    }
    out[sortedIdx[t]] = sum - a.w * 0.79788456080286535588f;
}

// ---------- launch ----------

extern "C" void kernel_launch(void* const* d_in, const int* in_sizes, int n_in,
                              void* d_out, int out_size, void* d_ws, size_t ws_size,
                              hipStream_t stream) {
    const float* cell = (const float*)d_in[0];
    const float* pos  = (const float*)d_in[1];
    const float* q    = (const float*)d_in[2];
    float* out = (float*)d_out;
    const int n = in_sizes[2];

    char* ws = (char*)d_ws;
    size_t o = 0;
    float4* sorted   = (float4*)(ws + o); o += (size_t)n * 16;
    int* sortedIdx   = (int*)(ws + o);    o += (size_t)n * 4;  o = (o + 255) & ~(size_t)255;
    int* hist        = (int*)(ws + o);    o += (size_t)BINS * 4;
    int* offsets     = (int*)(ws + o);    o += (size_t)(BINS + 1) * 4; o = (o + 255) & ~(size_t)255;
    int* cursor      = (int*)(ws + o);    o += (size_t)BINS * 4; o = (o + 255) & ~(size_t)255;
    float2* mesh     = (float2*)(ws + o); o += (size_t)NTOT * 8;
    float* rmesh     = (float*)(ws + o);  size_t o_real = o + (size_t)NTOT * 4;
    const bool haveReal = (ws_size >= o_real);

    zero_int_kernel<<<(BINS + 255) / 256, 256, 0, stream>>>(hist, BINS);
    hist_kernel<<<(n + 255) / 256, 256, 0, stream>>>(cell, pos, hist, n);
    scan_kernel<<<1, 256, 0, stream>>>(hist, offsets, cursor);
    reorder_kernel<<<(n + 255) / 256, 256, 0, stream>>>(cell, pos, q, cursor, sorted, sortedIdx, n);
    tile_scatter_kernel<<<NTILES, 512, 0, stream>>>(sorted, offsets, mesh);

    // forward z, y; fused (forward x + G + inverse x); inverse y, z
    fft_dit<-1, 2, false><<<2048, 512, 0, stream>>>(mesh, nullptr);
    fft_dit<-1, 1, false><<<2048, 512, 0, stream>>>(mesh, nullptr);
    fftX_G_kernel<<<2048, 512, 0, stream>>>(mesh, cell);
    fft_dit<1, 1, false><<<2048, 512, 0, stream>>>(mesh, nullptr);

    if (haveReal) {
        fft_dit<1, 2, true><<<2048, 512, 0, stream>>>(mesh, rmesh);
        gather_kernel<true><<<(n + 255) / 256, 256, 0, stream>>>(sorted, sortedIdx, mesh, rmesh, out, n);
    } else {
        fft_dit<1, 2, false><<<2048, 512, 0, stream>>>(mesh, nullptr);
        gather_kernel<false><<<(n + 255) / 256, 256, 0, stream>>>(sorted, sortedIdx, mesh, rmesh, out, n);
    }
}

// Round 4
// 215.772 us; speedup vs baseline: 4.5480x; 1.0608x over previous
//
#include <hip/hip_runtime.h>
#include <math.h>

#define NMESH 128
#define NTOT (128*128*128)
#define NBIN 32                 // bins per axis (4 cells per bin)
#define BINS (NBIN*NBIN*NBIN)

// scatter tiles: 16 x 16 x 8 cells
#define TSX 16
#define TSY 16
#define TSZ 8
#define NTILES (8*8*16)         // 1024
#define NSB 144                 // scanned bins per tile: 6*6*4
#define MAPCAP 3072

#define PI_F      3.14159265358979323846f
#define TWO_PI_F  6.28318530717958647692f
#define FOUR_PI_F 12.5663706143591729539f

// skewed LDS index for FFT lines
#define IDX(i) ((i) + ((i) >> 5))
#define LDSW 132

// ---------- helpers ----------

__device__ inline void inv3x3(const float* __restrict__ c, float* inv, float* detOut) {
    float a = c[0], b = c[1], cc = c[2];
    float d = c[3], e = c[4], f  = c[5];
    float g = c[6], h = c[7], i  = c[8];
    float A = e * i - f * h;
    float B = f * g - d * i;
    float C = d * h - e * g;
    float det = a * A + b * B + cc * C;
    float r = 1.0f / det;
    inv[0] = A * r;              inv[1] = (cc * h - b * i) * r;  inv[2] = (b * f - cc * e) * r;
    inv[3] = B * r;              inv[4] = (a * i - cc * g) * r;  inv[5] = (cc * d - a * f) * r;
    inv[6] = C * r;              inv[7] = (b * g - a * h) * r;   inv[8] = (a * e - b * d) * r;
    *detOut = det;
}

__device__ inline void w4(float x, float* w) {
    float x2 = x * x, x3 = x2 * x;
    w[0] = (1.0f  - 6.0f  * x + 12.0f * x2 - 8.0f  * x3) * (1.0f / 48.0f);
    w[1] = (23.0f - 30.0f * x - 12.0f * x2 + 24.0f * x3) * (1.0f / 48.0f);
    w[2] = (23.0f + 30.0f * x - 12.0f * x2 - 24.0f * x3) * (1.0f / 48.0f);
    w[3] = (1.0f  + 6.0f  * x + 12.0f * x2 + 8.0f  * x3) * (1.0f / 48.0f);
}

__device__ inline void atom_rel(const float* __restrict__ cell,
                                const float* __restrict__ pos, int t,
                                float* rx, float* ry, float* rz) {
    float inv[9]; float det;
    inv3x3(cell, inv, &det);
    float px = pos[3 * t], py = pos[3 * t + 1], pz = pos[3 * t + 2];
    *rx = (px * inv[0] + py * inv[3] + pz * inv[6]) * 128.0f;
    *ry = (px * inv[1] + py * inv[4] + pz * inv[7]) * 128.0f;
    *rz = (px * inv[2] + py * inv[5] + pz * inv[8]) * 128.0f;
}

__device__ inline int bin_of(float rx, float ry, float rz) {
    int ix = ((int)floorf(rx)) & 127;
    int iy = ((int)floorf(ry)) & 127;
    int iz = ((int)floorf(rz)) & 127;
    return ((ix >> 2) * NBIN + (iy >> 2)) * NBIN + (iz >> 2);
}

// ---------- binning ----------

__global__ void zero_int_kernel(int* __restrict__ p, int n) {
    int i = blockIdx.x * blockDim.x + threadIdx.x;
    if (i < n) p[i] = 0;
}

__global__ void hist_kernel(const float* __restrict__ cell, const float* __restrict__ pos,
                            int* __restrict__ hist, int n) {
    int t = blockIdx.x * blockDim.x + threadIdx.x;
    if (t >= n) return;
    float rx, ry, rz;
    atom_rel(cell, pos, t, &rx, &ry, &rz);
    atomicAdd(&hist[bin_of(rx, ry, rz)], 1);
}

__global__ __launch_bounds__(256) void scan_kernel(const int* __restrict__ hist,
                                                   int* __restrict__ offsets,
                                                   int* __restrict__ cursor) {
    const int PER = BINS / 256;
    int t = threadIdx.x;
    int base = t * PER;
    int s = 0;
    for (int i = 0; i < PER; ++i) s += hist[base + i];
    int lane = t & 63, wv = t >> 6;
    int v = s;
    #pragma unroll
    for (int d2 = 1; d2 < 64; d2 <<= 1) {
        int o = __shfl_up(v, d2, 64);
        if (lane >= d2) v += o;
    }
    __shared__ int wsum[4];
    if (lane == 63) wsum[wv] = v;
    __syncthreads();
    int add = 0;
    for (int k = 0; k < wv; ++k) add += wsum[k];
    int run = v - s + add;
    for (int i = 0; i < PER; ++i) {
        int b = base + i;
        offsets[b] = run; cursor[b] = run;
        run += hist[b];
    }
    if (t == 255) offsets[BINS] = run;
}

__global__ void reorder_kernel(const float* __restrict__ cell, const float* __restrict__ pos,
                               const float* __restrict__ q, int* __restrict__ cursor,
                               float4* __restrict__ sorted, int* __restrict__ sortedIdx, int n) {
    int t = blockIdx.x * blockDim.x + threadIdx.x;
    if (t >= n) return;
    float rx, ry, rz;
    atom_rel(cell, pos, t, &rx, &ry, &rz);
    int p = atomicAdd(&cursor[bin_of(rx, ry, rz)], 1);
    sorted[p] = make_float4(rx, ry, rz, q[t]);
    sortedIdx[p] = t;
}

// ---------- LDS-tiled scatter, flat work distribution ----------

__global__ __launch_bounds__(512) void tile_scatter_kernel(const float4* __restrict__ atoms,
                                                           const int* __restrict__ offsets,
                                                           float* __restrict__ rmesh) {
    const int tile = blockIdx.x;                 // 1024 tiles of 16x16x8 cells
    const int tz = tile & 15, ty = (tile >> 4) & 7, tx = tile >> 7;
    const int ox = tx << 4, oy = ty << 4, oz = tz << 3;

    __shared__ float acc[TSX * TSY * TSZ];       // [lx<<7 | ly<<3 | lz]
    __shared__ int   P[NSB + 1];                 // exclusive prefix of bin counts
    __shared__ int   bstart[NSB];                // global atom start per bin
    __shared__ int   sc[256];                    // scan scratch
    __shared__ unsigned short map[MAPCAP];       // local atom idx -> bin slot

    const int t = threadIdx.x;
    for (int c = t; c < TSX * TSY * TSZ; c += 512) acc[c] = 0.0f;

    int myCnt = 0;
    if (t < NSB) {
        int dx = t / 24, dy = (t / 4) % 6, dz = t & 3;
        int bx = (4 * tx - 1 + dx) & (NBIN - 1);
        int by = (4 * ty - 1 + dy) & (NBIN - 1);
        int bz = (2 * tz - 1 + dz) & (NBIN - 1);
        int bin = ((bx << 5) | by) << 5 | bz;
        int s = offsets[bin];
        bstart[t] = s;
        myCnt = offsets[bin + 1] - s;
    }
    if (t < 256) sc[t] = (t < NSB) ? myCnt : 0;
    __syncthreads();
    // Kogge-Stone inclusive scan over 256
    for (int off = 1; off < 256; off <<= 1) {
        int v = 0;
        if (t < 256 && t >= off) v = sc[t - off];
        __syncthreads();
        if (t < 256) sc[t] += v;
        __syncthreads();
    }
    if (t == 0) P[0] = 0;
    if (t < NSB) P[t + 1] = sc[t];
    __syncthreads();
    if (t < NSB) {
        int s = P[t], e = P[t + 1];
        if (e > MAPCAP) e = MAPCAP;
        for (int k = s; k < e; ++k) map[k] = (unsigned short)t;
    }
    __syncthreads();

    const int total = P[NSB];
    for (int i = t; i < total; i += 512) {
        int j;
        if (i < MAPCAP) {
            j = map[i];
        } else {                                   // statistically never
            int lo = 0, hi = NSB - 1;
            while (lo < hi) { int mid = (lo + hi + 1) >> 1; if (P[mid] <= i) lo = mid; else hi = mid - 1; }
            j = lo;
        }
        float4 a = atoms[bstart[j] + (i - P[j])];

        float w[4];
        float wxv[4], wyv[4], wzv[4];
        int lxv[4], lyv[4], lzv[4];
        int nx = 0, ny = 0, nz = 0;
        {
            float fl = floorf(a.x); int i0 = (int)fl; float x = a.x - fl - 0.5f; w4(x, w);
            #pragma unroll
            for (int s2 = 0; s2 < 4; ++s2) {
                int cc = (i0 + s2 - 1) & 127; int l = (cc - ox) & 127;
                if (l < TSX) { lxv[nx] = l << 7; wxv[nx++] = w[s2]; }
            }
        }
        {
            float fl = floorf(a.y); int i0 = (int)fl; float x = a.y - fl - 0.5f; w4(x, w);
            #pragma unroll
            for (int s2 = 0; s2 < 4; ++s2) {
                int cc = (i0 + s2 - 1) & 127; int l = (cc - oy) & 127;
                if (l < TSY) { lyv[ny] = l << 3; wyv[ny++] = w[s2]; }
            }
        }
        {
            float fl = floorf(a.z); int i0 = (int)fl; float x = a.z - fl - 0.5f; w4(x, w);
            #pragma unroll
            for (int s2 = 0; s2 < 4; ++s2) {
                int cc = (i0 + s2 - 1) & 127; int l = (cc - oz) & 127;
                if (l < TSZ) { lzv[nz] = l; wzv[nz++] = w[s2]; }
            }
        }
        if (nx == 0 || ny == 0 || nz == 0) continue;
        float qc = a.w;
        for (int i2 = 0; i2 < nx; ++i2) {
            float qx = qc * wxv[i2];
            for (int j2 = 0; j2 < ny; ++j2) {
                float qxy = qx * wyv[j2];
                int b = lxv[i2] | lyv[j2];
                for (int k = 0; k < nz; ++k)
                    atomicAdd(&acc[b | lzv[k]], qxy * wzv[k]);
            }
        }
    }
    __syncthreads();

    for (int c = t; c < TSX * TSY * TSZ; c += 512) {
        int lx = c >> 7, ly = (c >> 3) & 15, lz = c & 7;
        int g = ((ox + lx) << 14) | ((oy + ly) << 7) | (oz + lz);
        rmesh[g] = acc[c];
    }
}

// ---------- batched FFT: 16 lines per 1024-thread block ----------
// AXIS==2: z-lines; AXIS==1: y-lines, 16 consecutive z per block (128B coalesced)

template<int AXIS>
__device__ inline size_t addr16(int b, int l, int e) {
    if (AXIS == 2) return ((size_t)b << 11) + ((size_t)l << 7) + (size_t)e;
    return ((size_t)(b >> 3) << 14) + ((size_t)e << 7) + (size_t)(((b & 7) << 4) + l);
}

// RM: 0 = complex->complex, 1 = real in, 2 = real out
template<int SIGN, int AXIS, int RM>
__global__ __launch_bounds__(1024) void fft_dit16(float2* __restrict__ d, float* __restrict__ rm) {
    __shared__ float re[16][LDSW], im[16][LDSW];
    const int t = threadIdx.x, b = blockIdx.x;

    for (int u = t; u < 2048; u += 1024) {
        int l, e;
        if (AXIS == 2) { l = u >> 7; e = u & 127; } else { l = u & 15; e = u >> 4; }
        int r = (int)(__brev((unsigned)e) >> 25);
        if (RM == 1) {
            float v = rm[addr16<AXIS>(b, l, e)];
            re[l][IDX(r)] = v; im[l][IDX(r)] = 0.0f;
        } else {
            float2 v = d[addr16<AXIS>(b, l, e)];
            re[l][IDX(r)] = v.x; im[l][IDX(r)] = v.y;
        }
    }
    __syncthreads();

    const int w = t >> 6, lane = t & 63;
    #pragma unroll
    for (int s = 1; s <= 7; ++s) {
        int half = 1 << (s - 1);
        int pos = lane & (half - 1);
        int i = ((lane >> (s - 1)) << s) | pos;
        int j = i + half;
        float ang = (float)SIGN * PI_F * (float)pos / (float)half;
        float sn, cs; __sincosf(ang, &sn, &cs);
        int ii = IDX(i), jj = IDX(j);
        float ar = re[w][jj], ai = im[w][jj];
        float tr = cs * ar - sn * ai;
        float ti = cs * ai + sn * ar;
        float br = re[w][ii], bi = im[w][ii];
        re[w][jj] = br - tr; im[w][jj] = bi - ti;
        re[w][ii] = br + tr; im[w][ii] = bi + ti;
        __syncthreads();
    }

    for (int u = t; u < 2048; u += 1024) {
        int l, e;
        if (AXIS == 2) { l = u >> 7; e = u & 127; } else { l = u & 15; e = u >> 4; }
        if (RM == 2) rm[addr16<AXIS>(b, l, e)] = re[l][IDX(e)];
        else d[addr16<AXIS>(b, l, e)] = make_float2(re[l][IDX(e)], im[l][IDX(e)]);
    }
}

// Fused x-axis: forward DIF -> G(k) multiply (bit-reversed order) -> inverse DIT.
__global__ __launch_bounds__(1024) void fftX_G_kernel(float2* __restrict__ d,
                                                      const float* __restrict__ cell) {
    __shared__ float re[16][LDSW], im[16][LDSW];
    const int t = threadIdx.x, b = blockIdx.x;
    const int y = b >> 3, z0 = (b & 7) << 4;

    for (int u = t; u < 2048; u += 1024) {
        int l = u & 15, e = u >> 4;
        float2 v = d[((size_t)e << 14) + (size_t)(y << 7) + (size_t)(z0 + l)];
        re[l][IDX(e)] = v.x; im[l][IDX(e)] = v.y;
    }
    __syncthreads();

    const int w = t >> 6, lane = t & 63;

    // forward DIF (natural -> bit-reversed), sign = -1
    #pragma unroll
    for (int s = 7; s >= 1; --s) {
        int half = 1 << (s - 1);
        int pos = lane & (half - 1);
        int i = ((lane >> (s - 1)) << s) | pos;
        int j = i + half;
        float ang = -PI_F * (float)pos / (float)half;
        float sn, cs; __sincosf(ang, &sn, &cs);
        int ii = IDX(i), jj = IDX(j);
        float ar = re[w][ii], ai = im[w][ii];
        float br = re[w][jj], bi = im[w][jj];
        re[w][ii] = ar + br;   im[w][ii] = ai + bi;
        float dr = ar - br, di = ai - bi;
        re[w][jj] = cs * dr - sn * di;
        im[w][jj] = cs * di + sn * dr;
        __syncthreads();
    }

    // G(k): LDS pos p holds kx-index rev7(p); line w: ky=y, kz=z0+w
    {
        float inv[9]; float det; inv3x3(cell, inv, &det);
        float invVol = 1.0f / fabsf(det);
        int my = y, mz = z0 + w;
        float fy = (my < 64) ? (float)my : (float)(my - 128);
        float fz = (mz < 64) ? (float)mz : (float)(mz - 128);
        for (int p = lane; p < 128; p += 64) {
            int mx = (int)(__brev((unsigned)p) >> 25);
            float fx = (mx < 64) ? (float)mx : (float)(mx - 128);
            float kx = TWO_PI_F * (fx * inv[0] + fy * inv[1] + fz * inv[2]);
            float ky = TWO_PI_F * (fx * inv[3] + fy * inv[4] + fz * inv[5]);
            float kz = TWO_PI_F * (fx * inv[6] + fy * inv[7] + fz * inv[8]);
            float ksq = kx * kx + ky * ky + kz * kz;
            float G = (ksq == 0.0f) ? 0.0f
                      : FOUR_PI_F / ksq * __expf(-0.5f * ksq) * invVol;
            re[w][IDX(p)] *= G; im[w][IDX(p)] *= G;
        }
    }
    __syncthreads();

    // inverse DIT (bit-reversed -> natural), sign = +1
    #pragma unroll
    for (int s = 1; s <= 7; ++s) {
        int half = 1 << (s - 1);
        int pos = lane & (half - 1);
        int i = ((lane >> (s - 1)) << s) | pos;
        int j = i + half;
        float ang = PI_F * (float)pos / (float)half;
        float sn, cs; __sincosf(ang, &sn, &cs);
        int ii = IDX(i), jj = IDX(j);
        float ar = re[w][jj], ai = im[w][jj];
        float tr = cs * ar - sn * ai;
        float ti = cs * ai + sn * ar;
        float br = re[w][ii], bi = im[w][ii];
        re[w][jj] = br - tr; im[w][jj] = bi - ti;
        re[w][ii] = br + tr; im[w][ii] = bi + ti;
        __syncthreads();
    }

    for (int u = t; u < 2048; u += 1024) {
        int l = u & 15, e = u >> 4;
        d[((size_t)e << 14) + (size_t)(y << 7) + (size_t)(z0 + l)] =
            make_float2(re[l][IDX(e)], im[l][IDX(e)]);
    }
}

// ---------- gather ----------

__global__ void gather_kernel(const float4* __restrict__ sorted, const int* __restrict__ sortedIdx,
                              const float* __restrict__ rmesh, float* __restrict__ out, int n) {
    int t = blockIdx.x * blockDim.x + threadIdx.x;
    if (t >= n) return;
    float4 a = sorted[t];
    float wx[4], wy[4], wz[4];
    int ix[4], iy[4], iz[4];
    {
        float fl = floorf(a.x); int i0 = (int)fl; float x = a.x - fl - 0.5f; w4(x, wx);
        #pragma unroll
        for (int s = 0; s < 4; ++s) ix[s] = (i0 + s - 1) & 127;
    }
    {
        float fl = floorf(a.y); int i0 = (int)fl; float x = a.y - fl - 0.5f; w4(x, wy);
        #pragma unroll
        for (int s = 0; s < 4; ++s) iy[s] = (i0 + s - 1) & 127;
    }
    {
        float fl = floorf(a.z); int i0 = (int)fl; float x = a.z - fl - 0.5f; w4(x, wz);
        #pragma unroll
        for (int s = 0; s < 4; ++s) iz[s] = (i0 + s - 1) & 127;
    }
    float sum = 0.0f;
    #pragma unroll
    for (int i = 0; i < 4; ++i) {
        int bx = ix[i] << 14;
        float acc_i = 0.0f;
        #pragma unroll
        for (int j = 0; j < 4; ++j) {
            int bxy = bx | (iy[j] << 7);
            float acc_j = 0.0f;
            #pragma unroll
            for (int k = 0; k < 4; ++k) {
                acc_j += wz[k] * rmesh[bxy | iz[k]];
            }
            acc_i += wy[j] * acc_j;
        }
        sum += wx[i] * acc_i;
    }
    out[sortedIdx[t]] = sum - a.w * 0.79788456080286535588f;
}

// ---------- launch ----------

extern "C" void kernel_launch(void* const* d_in, const int* in_sizes, int n_in,
                              void* d_out, int out_size, void* d_ws, size_t ws_size,
                              hipStream_t stream) {
    const float* cell = (const float*)d_in[0];
    const float* pos  = (const float*)d_in[1];
    const float* q    = (const float*)d_in[2];
    float* out = (float*)d_out;
    const int n = in_sizes[2];

    char* ws = (char*)d_ws;
    size_t o = 0;
    float4* sorted   = (float4*)(ws + o); o += (size_t)n * 16;
    int* sortedIdx   = (int*)(ws + o);    o += (size_t)n * 4;  o = (o + 255) & ~(size_t)255;
    int* hist        = (int*)(ws + o);    o += (size_t)BINS * 4;
    int* offsets     = (int*)(ws + o);    o += (size_t)(BINS + 1) * 4; o = (o + 255) & ~(size_t)255;
    int* cursor      = (int*)(ws + o);    o += (size_t)BINS * 4; o = (o + 255) & ~(size_t)255;
    float2* mesh     = (float2*)(ws + o); o += (size_t)NTOT * 8;
    float* rmesh     = (float*)(ws + o);  // NTOT * 4 — validated to fit in round 3

    zero_int_kernel<<<(BINS + 255) / 256, 256, 0, stream>>>(hist, BINS);
    hist_kernel<<<(n + 255) / 256, 256, 0, stream>>>(cell, pos, hist, n);
    scan_kernel<<<1, 256, 0, stream>>>(hist, offsets, cursor);
    reorder_kernel<<<(n + 255) / 256, 256, 0, stream>>>(cell, pos, q, cursor, sorted, sortedIdx, n);
    tile_scatter_kernel<<<NTILES, 512, 0, stream>>>(sorted, offsets, rmesh);

    // forward z (real in), y; fused (fwd x + G + inv x); inverse y, z (real out)
    fft_dit16<-1, 2, 1><<<1024, 1024, 0, stream>>>(mesh, rmesh);
    fft_dit16<-1, 1, 0><<<1024, 1024, 0, stream>>>(mesh, nullptr);
    fftX_G_kernel<<<1024, 1024, 0, stream>>>(mesh, cell);
    fft_dit16<1, 1, 0><<<1024, 1024, 0, stream>>>(mesh, nullptr);
    fft_dit16<1, 2, 2><<<1024, 1024, 0, stream>>>(mesh, rmesh);

    gather_kernel<<<(n + 255) / 256, 256, 0, stream>>>(sorted, sortedIdx, rmesh, out, n);
}